// Round 2
// baseline (307.355 us; speedup 1.0000x reference)
//
#include <hip/hip_runtime.h>
#include <hip/hip_bf16.h>

#define NT 768
#define ND 256
#define PD 128
#define NH 8
#define DH 32
#define NPAIR 589824   // 768*768

// workspace offsets (floats)
#define WS_X     0
#define WS_Q     196608
#define WS_K     393216
#define WS_V     589824
#define WS_GATE  786432
#define WS_AOUT  983040
#define WS_BIAS  1179648
// total = 1179648 + 8*589824 = 5898240 floats = 23.6 MB

// ---------------- K1: LayerNorm(node) -> x ----------------
__global__ __launch_bounds__(256) void k_ln_node(const float* __restrict__ nf,
                                                 const float* __restrict__ w,
                                                 const float* __restrict__ b,
                                                 float* __restrict__ x) {
  int i = blockIdx.x, t = threadIdx.x;
  float v = nf[i * ND + t];
  float s1 = v, s2 = v * v;
#pragma unroll
  for (int m = 1; m < 64; m <<= 1) { s1 += __shfl_xor(s1, m); s2 += __shfl_xor(s2, m); }
  __shared__ float a1[4], a2[4];
  if ((t & 63) == 0) { a1[t >> 6] = s1; a2[t >> 6] = s2; }
  __syncthreads();
  s1 = a1[0] + a1[1] + a1[2] + a1[3];
  s2 = a2[0] + a2[1] + a2[2] + a2[3];
  float mu = s1 * (1.f / ND);
  float var = s2 * (1.f / ND) - mu * mu;
  float rs = rsqrtf(var + 1e-5f);
  x[i * ND + t] = (v - mu) * rs * w[t] + b[t];
}

// ---------------- K2: x @ [w_qkv | w_g] -> q,k,v (h,i,d) + sigmoid gate ----------------
__global__ __launch_bounds__(256) void k_qkvg(const float* __restrict__ x,
                                              const float* __restrict__ wqkv,
                                              const float* __restrict__ wg,
                                              const float* __restrict__ bg,
                                              float* __restrict__ ws) {
  __shared__ __align__(16) float As[16 * 64];
  __shared__ __align__(16) float Bs[16 * 64];
  int n0 = blockIdx.x * 64, i0 = blockIdx.y * 64, t = threadIdx.x;
  bool isg = (n0 >= 768);
  const float* W = isg ? wg : wqkv;
  int ldb = isg ? 256 : 768;
  int nc0 = isg ? n0 - 768 : n0;
  int tm = t >> 4, tn = t & 15;
  int sm = t >> 2, sk = (t & 3) * 4;
  int bk = t >> 4, bn = (t & 15) * 4;
  float acc[4][4] = {{0.f}};
  for (int k0 = 0; k0 < 256; k0 += 16) {
    float4 av = *(const float4*)&x[(i0 + sm) * 256 + k0 + sk];
    float4 bv = *(const float4*)&W[(size_t)(k0 + bk) * ldb + nc0 + bn];
    __syncthreads();
    As[(sk + 0) * 64 + sm] = av.x; As[(sk + 1) * 64 + sm] = av.y;
    As[(sk + 2) * 64 + sm] = av.z; As[(sk + 3) * 64 + sm] = av.w;
    *(float4*)&Bs[bk * 64 + bn] = bv;
    __syncthreads();
#pragma unroll
    for (int kk = 0; kk < 16; ++kk) {
      float4 a4 = *(float4*)&As[kk * 64 + tm * 4];
      float4 b4 = *(float4*)&Bs[kk * 64 + tn * 4];
      float ar[4] = {a4.x, a4.y, a4.z, a4.w};
      float br[4] = {b4.x, b4.y, b4.z, b4.w};
#pragma unroll
      for (int ii = 0; ii < 4; ++ii)
#pragma unroll
        for (int jj = 0; jj < 4; ++jj) acc[ii][jj] = fmaf(ar[ii], br[jj], acc[ii][jj]);
    }
  }
#pragma unroll
  for (int ii = 0; ii < 4; ++ii) {
    int i = i0 + tm * 4 + ii;
#pragma unroll
    for (int jj = 0; jj < 4; ++jj) {
      int o = n0 + tn * 4 + jj;
      float val = acc[ii][jj];
      if (!isg) {
        int which = o >> 8, inner = o & 255, h = inner >> 5, d = inner & 31;
        float* dst = ws + (which == 0 ? WS_Q : (which == 1 ? WS_K : WS_V));
        float sc = (which == 0) ? 0.17677669529663687f : 1.f;  // 1/sqrt(32) on q
        dst[(h * NT + i) * DH + d] = val * sc;
      } else {
        int inner = nc0 + tn * 4 + jj;
        val += bg[inner];
        ws[WS_GATE + i * ND + inner] = 1.f / (1.f + __expf(-val));
      }
    }
  }
}

// ---------------- K3: fused LN(pair) @ w_bias + mask fold -> bias (h,i,j) ----------------
// bias[h] = rs*(dot(p, ln_w*wb[:,h]) - mu*c1[h]) + c0[h];  masked -> -1e30
__global__ __launch_bounds__(256) void k_pair_bias(const float* __restrict__ pf,
                                                   const int* __restrict__ mask,
                                                   const float* __restrict__ lnw,
                                                   const float* __restrict__ lnb,
                                                   const float* __restrict__ wb,
                                                   float* __restrict__ bias_out) {
  __shared__ __align__(16) float P[96 * 128];    // 48 KB, XOR-swizzled 16B chunks
  __shared__ __align__(16) float WPT[8 * 128];   // wpt[h][e] = ln_w[e]*wb[e][h]
  __shared__ float C0[8], C1[8];
  int t = threadIdx.x;
  size_t base = (size_t)blockIdx.x * (96 * 128);
  const float4* src = (const float4*)(pf + base);
#pragma unroll
  for (int it = 0; it < 12; ++it) {                 // stage 96 rows coalesced
    int f = it * 256 + t;
    int r = f >> 5, c4 = f & 31;
    float4 vv = src[f];
    *(float4*)&P[r * 128 + (c4 ^ (r & 7)) * 4] = vv;  // swizzle vs 32-way conflict
  }
#pragma unroll
  for (int it = 0; it < 4; ++it) {
    int idx = it * 256 + t;
    int hh = idx >> 7, e = idx & 127;
    WPT[hh * 128 + e] = lnw[e] * wb[e * 8 + hh];
  }
  __syncthreads();
  if (t < 8) {
    float c0 = 0.f, c1 = 0.f;
    for (int e = 0; e < 128; ++e) { c1 += WPT[t * 128 + e]; c0 += lnb[e] * wb[e * 8 + t]; }
    C0[t] = c0; C1[t] = c1;
  }
  __syncthreads();
  if (t < 192) {                                   // 2 threads per row
    int r = t >> 1, half = t & 1;
    size_t g = (size_t)blockIdx.x * 96 + r;
    float s1 = 0.f, s2 = 0.f;
    float d[8] = {0.f, 0.f, 0.f, 0.f, 0.f, 0.f, 0.f, 0.f};
#pragma unroll
    for (int kk = 0; kk < 16; ++kk) {
      int e4 = half * 16 + kk;
      float4 p = *(float4*)&P[r * 128 + (e4 ^ (r & 7)) * 4];
      s1 += p.x + p.y + p.z + p.w;
      s2 += p.x * p.x + p.y * p.y + p.z * p.z + p.w * p.w;
#pragma unroll
      for (int hh = 0; hh < 8; ++hh) {
        float4 w4 = *(float4*)&WPT[hh * 128 + e4 * 4];  // broadcast read
        d[hh] = fmaf(p.x, w4.x, fmaf(p.y, w4.y, fmaf(p.z, w4.z, fmaf(p.w, w4.w, d[hh]))));
      }
    }
    s1 += __shfl_xor(s1, 1);
    s2 += __shfl_xor(s2, 1);
#pragma unroll
    for (int hh = 0; hh < 8; ++hh) d[hh] += __shfl_xor(d[hh], 1);
    if (half == 0) {
      float mu = s1 * (1.f / 128.f);
      float var = s2 * (1.f / 128.f) - mu * mu;
      float rs = rsqrtf(var + 1e-5f);
      int mk = mask[g];
#pragma unroll
      for (int hh = 0; hh < 8; ++hh) {
        float bvv = rs * (d[hh] - mu * C1[hh]) + C0[hh];
        if (mk == 0) bvv = -1e30f;
        bias_out[(size_t)hh * NPAIR + g] = bvv;
      }
    }
  }
}

// ---------------- K4: per (head, 16-row tile) attention + gate ----------------
__global__ __launch_bounds__(256) void k_attn(const float* __restrict__ q,
                                              const float* __restrict__ k,
                                              const float* __restrict__ v,
                                              const float* __restrict__ gate,
                                              const float* __restrict__ bias,
                                              float* __restrict__ aout) {
  __shared__ __align__(16) float SIM[16 * 772];  // padded stride vs bank conflicts
  __shared__ __align__(16) float QS[16 * 32];
  int i0 = blockIdx.x * 16, h = blockIdx.y, t = threadIdx.x;
  int tr = t >> 4, tc = t & 15;
  for (int idx = t; idx < 512; idx += 256) {
    int r = idx >> 5, d = idx & 31;
    QS[r * 32 + d] = q[((size_t)h * NT + i0 + r) * DH + d];
  }
  __syncthreads();
  float4 qr[8];
#pragma unroll
  for (int e = 0; e < 8; ++e) qr[e] = *(float4*)&QS[tr * 32 + e * 4];
  const float* Kh = k + (size_t)h * NT * DH;
  const float* Vh = v + (size_t)h * NT * DH;
  const float* brow = bias + ((size_t)h * NT + i0 + tr) * NT;
  float mx = -3.4e38f;
  for (int j = tc; j < NT; j += 16) {
    const float4* kr = (const float4*)(Kh + j * DH);
    float s = 0.f;
#pragma unroll
    for (int e = 0; e < 8; ++e) {
      float4 kv = kr[e];
      s += qr[e].x * kv.x + qr[e].y * kv.y + qr[e].z * kv.z + qr[e].w * kv.w;
    }
    s += brow[j];                     // q pre-scaled; bias carries mask fold
    SIM[tr * 772 + j] = s;
    mx = fmaxf(mx, s);
  }
#pragma unroll
  for (int m = 1; m < 16; m <<= 1) mx = fmaxf(mx, __shfl_xor(mx, m));
  float sum = 0.f;
  for (int j = tc; j < NT; j += 16) {
    float p = __expf(SIM[tr * 772 + j] - mx);
    SIM[tr * 772 + j] = p;
    sum += p;
  }
#pragma unroll
  for (int m = 1; m < 16; m <<= 1) sum += __shfl_xor(sum, m);
  float inv = 1.f / sum;
  __syncthreads();                    // SIM fully visible for PV
  float acc0 = 0.f, acc1 = 0.f;
#pragma unroll 4
  for (int j = 0; j < NT; ++j) {
    float p = SIM[tr * 772 + j];
    acc0 = fmaf(p, Vh[j * DH + tc], acc0);
    acc1 = fmaf(p, Vh[j * DH + tc + 16], acc1);
  }
  acc0 *= inv; acc1 *= inv;
  int i = i0 + tr;
  float g0 = gate[i * ND + h * DH + tc];
  float g1 = gate[i * ND + h * DH + tc + 16];
  aout[i * ND + h * DH + tc] = acc0 * g0;
  aout[i * ND + h * DH + tc + 16] = acc1 * g1;
}

// ---------------- K5: aout @ w_out + b_out -> fp32 output ----------------
__global__ __launch_bounds__(256) void k_proj(const float* __restrict__ a,
                                              const float* __restrict__ w,
                                              const float* __restrict__ b,
                                              float* __restrict__ out) {
  __shared__ __align__(16) float As[16 * 64];
  __shared__ __align__(16) float Bs[16 * 64];
  int n0 = blockIdx.x * 64, i0 = blockIdx.y * 64, t = threadIdx.x;
  int tm = t >> 4, tn = t & 15;
  int sm = t >> 2, sk = (t & 3) * 4;
  int bk = t >> 4, bn = (t & 15) * 4;
  float acc[4][4] = {{0.f}};
  for (int k0 = 0; k0 < 256; k0 += 16) {
    float4 av = *(const float4*)&a[(i0 + sm) * 256 + k0 + sk];
    float4 bv = *(const float4*)&w[(k0 + bk) * 256 + n0 + bn];
    __syncthreads();
    As[(sk + 0) * 64 + sm] = av.x; As[(sk + 1) * 64 + sm] = av.y;
    As[(sk + 2) * 64 + sm] = av.z; As[(sk + 3) * 64 + sm] = av.w;
    *(float4*)&Bs[bk * 64 + bn] = bv;
    __syncthreads();
#pragma unroll
    for (int kk = 0; kk < 16; ++kk) {
      float4 a4 = *(float4*)&As[kk * 64 + tm * 4];
      float4 b4 = *(float4*)&Bs[kk * 64 + tn * 4];
      float ar[4] = {a4.x, a4.y, a4.z, a4.w};
      float br[4] = {b4.x, b4.y, b4.z, b4.w};
#pragma unroll
      for (int ii = 0; ii < 4; ++ii)
#pragma unroll
        for (int jj = 0; jj < 4; ++jj) acc[ii][jj] = fmaf(ar[ii], br[jj], acc[ii][jj]);
    }
  }
#pragma unroll
  for (int ii = 0; ii < 4; ++ii) {
    int i = i0 + tm * 4 + ii;
#pragma unroll
    for (int jj = 0; jj < 4; ++jj) {
      int o = n0 + tn * 4 + jj;
      out[i * 256 + o] = acc[ii][jj] + b[o];
    }
  }
}

extern "C" void kernel_launch(void* const* d_in, const int* in_sizes, int n_in,
                              void* d_out, int out_size, void* d_ws, size_t ws_size,
                              hipStream_t stream) {
  const float* node   = (const float*)d_in[0];
  const float* pair   = (const float*)d_in[1];
  const int*   mask   = (const int*)d_in[2];
  const float* ln_nw  = (const float*)d_in[3];
  const float* ln_nb  = (const float*)d_in[4];
  const float* ln_pw  = (const float*)d_in[5];
  const float* ln_pb  = (const float*)d_in[6];
  const float* w_qkv  = (const float*)d_in[7];
  const float* w_g    = (const float*)d_in[8];
  const float* b_g    = (const float*)d_in[9];
  const float* w_bias = (const float*)d_in[10];
  const float* w_out  = (const float*)d_in[11];
  const float* b_out  = (const float*)d_in[12];
  float* ws = (float*)d_ws;
  float* out = (float*)d_out;

  k_ln_node<<<NT, 256, 0, stream>>>(node, ln_nw, ln_nb, ws + WS_X);
  k_qkvg<<<dim3(16, 12), 256, 0, stream>>>(ws + WS_X, w_qkv, w_g, b_g, ws);
  k_pair_bias<<<NPAIR / 96, 256, 0, stream>>>(pair, mask, ln_pw, ln_pb, w_bias, ws + WS_BIAS);
  k_attn<<<dim3(48, 8), 256, 0, stream>>>(ws + WS_Q, ws + WS_K, ws + WS_V,
                                          ws + WS_GATE, ws + WS_BIAS, ws + WS_AOUT);
  k_proj<<<dim3(4, 12), 256, 0, stream>>>(ws + WS_AOUT, w_out, b_out, out);
}

// Round 3
// 272.389 us; speedup vs baseline: 1.1284x; 1.1284x over previous
//
#include <hip/hip_runtime.h>
#include <hip/hip_bf16.h>

#define NT 768
#define ND 256
#define PD 128
#define NH 8
#define DH 32
#define NPAIR 589824   // 768*768

// workspace offsets (floats)
#define WS_X     0
#define WS_Q     196608
#define WS_K     393216
#define WS_V     589824
#define WS_GATE  786432
#define WS_AOUT  983040
#define WS_BIAS  1179648
// total = 1179648 + 8*589824 = 5898240 floats = 23.6 MB

// ---------------- K1: LayerNorm(node) -> x ----------------
__global__ __launch_bounds__(256) void k_ln_node(const float* __restrict__ nf,
                                                 const float* __restrict__ w,
                                                 const float* __restrict__ b,
                                                 float* __restrict__ x) {
  int i = blockIdx.x, t = threadIdx.x;
  float v = nf[i * ND + t];
  float s1 = v, s2 = v * v;
#pragma unroll
  for (int m = 1; m < 64; m <<= 1) { s1 += __shfl_xor(s1, m); s2 += __shfl_xor(s2, m); }
  __shared__ float a1[4], a2[4];
  if ((t & 63) == 0) { a1[t >> 6] = s1; a2[t >> 6] = s2; }
  __syncthreads();
  s1 = a1[0] + a1[1] + a1[2] + a1[3];
  s2 = a2[0] + a2[1] + a2[2] + a2[3];
  float mu = s1 * (1.f / ND);
  float var = s2 * (1.f / ND) - mu * mu;
  float rs = rsqrtf(var + 1e-5f);
  x[i * ND + t] = (v - mu) * rs * w[t] + b[t];
}

// ---------------- K2: x @ [w_qkv | w_g] -> q,k,v (h,i,d) + sigmoid gate ----------------
__global__ __launch_bounds__(256) void k_qkvg(const float* __restrict__ x,
                                              const float* __restrict__ wqkv,
                                              const float* __restrict__ wg,
                                              const float* __restrict__ bg,
                                              float* __restrict__ ws) {
  __shared__ __align__(16) float As[16 * 64];
  __shared__ __align__(16) float Bs[16 * 64];
  int n0 = blockIdx.x * 64, i0 = blockIdx.y * 64, t = threadIdx.x;
  bool isg = (n0 >= 768);
  const float* W = isg ? wg : wqkv;
  int ldb = isg ? 256 : 768;
  int nc0 = isg ? n0 - 768 : n0;
  int tm = t >> 4, tn = t & 15;
  int sm = t >> 2, sk = (t & 3) * 4;
  int bk = t >> 4, bn = (t & 15) * 4;
  float acc[4][4] = {{0.f}};
  for (int k0 = 0; k0 < 256; k0 += 16) {
    float4 av = *(const float4*)&x[(i0 + sm) * 256 + k0 + sk];
    float4 bv = *(const float4*)&W[(size_t)(k0 + bk) * ldb + nc0 + bn];
    __syncthreads();
    As[(sk + 0) * 64 + sm] = av.x; As[(sk + 1) * 64 + sm] = av.y;
    As[(sk + 2) * 64 + sm] = av.z; As[(sk + 3) * 64 + sm] = av.w;
    *(float4*)&Bs[bk * 64 + bn] = bv;
    __syncthreads();
#pragma unroll
    for (int kk = 0; kk < 16; ++kk) {
      float4 a4 = *(float4*)&As[kk * 64 + tm * 4];
      float4 b4 = *(float4*)&Bs[kk * 64 + tn * 4];
      float ar[4] = {a4.x, a4.y, a4.z, a4.w};
      float br[4] = {b4.x, b4.y, b4.z, b4.w};
#pragma unroll
      for (int ii = 0; ii < 4; ++ii)
#pragma unroll
        for (int jj = 0; jj < 4; ++jj) acc[ii][jj] = fmaf(ar[ii], br[jj], acc[ii][jj]);
    }
  }
#pragma unroll
  for (int ii = 0; ii < 4; ++ii) {
    int i = i0 + tm * 4 + ii;
#pragma unroll
    for (int jj = 0; jj < 4; ++jj) {
      int o = n0 + tn * 4 + jj;
      float val = acc[ii][jj];
      if (!isg) {
        int which = o >> 8, inner = o & 255, h = inner >> 5, d = inner & 31;
        float* dst = ws + (which == 0 ? WS_Q : (which == 1 ? WS_K : WS_V));
        float sc = (which == 0) ? 0.17677669529663687f : 1.f;  // 1/sqrt(32) on q
        dst[(h * NT + i) * DH + d] = val * sc;
      } else {
        int inner = nc0 + tn * 4 + jj;
        val += bg[inner];
        ws[WS_GATE + i * ND + inner] = 1.f / (1.f + __expf(-val));
      }
    }
  }
}

// ---------------- K3: fused LN(pair) @ w_bias + mask fold -> bias (h,i,j) ----------------
// bias[h] = rs*(dot(p, ln_w*wb[:,h]) - mu*c1[h]) + c0[h];  masked -> -1e30
// Register-tiled: 48 compute threads, each 4 rows {k,k+24,k+48,k+72} x 4 heads.
__global__ __launch_bounds__(256) void k_pair_bias(const float* __restrict__ pf,
                                                   const int* __restrict__ mask,
                                                   const float* __restrict__ lnw,
                                                   const float* __restrict__ lnb,
                                                   const float* __restrict__ wb,
                                                   float* __restrict__ bias_out) {
  __shared__ __align__(16) float P[96 * 128];    // 48 KB, ADD-rotate swizzled 16B slots
  __shared__ __align__(16) float WPT[8 * 128];   // wpt[h][e] = ln_w[e]*wb[e][h]
  __shared__ float C0s[8], C1s[8];
  int t = threadIdx.x;
  size_t base = (size_t)blockIdx.x * (96 * 128);
  const float4* src = (const float4*)(pf + base);
#pragma unroll
  for (int it = 0; it < 12; ++it) {                 // stage 96 rows coalesced
    int f = it * 256 + t;
    int r = f >> 5, c4 = f & 31;
    float4 vv = src[f];
    *(float4*)&P[r * 128 + ((c4 + r) & 31) * 4] = vv;  // full 32-slot rotate swizzle
  }
#pragma unroll
  for (int it = 0; it < 4; ++it) {
    int idx = it * 256 + t;
    int hh = idx >> 7, e = idx & 127;
    WPT[hh * 128 + e] = lnw[e] * wb[e * 8 + hh];
  }
  __syncthreads();
  if (t < 8) {
    float c0 = 0.f, c1 = 0.f;
    for (int e = 0; e < 128; ++e) { c1 += WPT[t * 128 + e]; c0 += lnb[e] * wb[e * 8 + t]; }
    C0s[t] = c0; C1s[t] = c1;
  }
  __syncthreads();
  if (t < 48) {
    int k = t >> 1, hq = (t & 1) * 4;               // 24 row-sets x 2 head-quads
    float s1[4] = {0.f, 0.f, 0.f, 0.f};
    float s2[4] = {0.f, 0.f, 0.f, 0.f};
    float d[4][4] = {{0.f}};
#pragma unroll
    for (int e4 = 0; e4 < 32; ++e4) {
      float4 w0 = *(float4*)&WPT[(hq + 0) * 128 + e4 * 4];   // broadcast (2 addrs/wave)
      float4 w1 = *(float4*)&WPT[(hq + 1) * 128 + e4 * 4];
      float4 w2 = *(float4*)&WPT[(hq + 2) * 128 + e4 * 4];
      float4 w3 = *(float4*)&WPT[(hq + 3) * 128 + e4 * 4];
#pragma unroll
      for (int i = 0; i < 4; ++i) {
        int r = k + 24 * i;
        float4 p = *(float4*)&P[r * 128 + ((e4 + r) & 31) * 4];  // 24 distinct slots, 2-way
        s1[i] += p.x + p.y + p.z + p.w;
        s2[i] = fmaf(p.x, p.x, fmaf(p.y, p.y, fmaf(p.z, p.z, fmaf(p.w, p.w, s2[i]))));
        d[i][0] = fmaf(p.x, w0.x, fmaf(p.y, w0.y, fmaf(p.z, w0.z, fmaf(p.w, w0.w, d[i][0]))));
        d[i][1] = fmaf(p.x, w1.x, fmaf(p.y, w1.y, fmaf(p.z, w1.z, fmaf(p.w, w1.w, d[i][1]))));
        d[i][2] = fmaf(p.x, w2.x, fmaf(p.y, w2.y, fmaf(p.z, w2.z, fmaf(p.w, w2.w, d[i][2]))));
        d[i][3] = fmaf(p.x, w3.x, fmaf(p.y, w3.y, fmaf(p.z, w3.z, fmaf(p.w, w3.w, d[i][3]))));
      }
    }
#pragma unroll
    for (int i = 0; i < 4; ++i) {
      int r = k + 24 * i;
      size_t g = (size_t)blockIdx.x * 96 + r;
      float mu = s1[i] * (1.f / 128.f);
      float var = s2[i] * (1.f / 128.f) - mu * mu;
      float rs = rsqrtf(var + 1e-5f);
      int mk = mask[g];
#pragma unroll
      for (int j = 0; j < 4; ++j) {
        int hh = hq + j;
        float bvv = rs * (d[i][j] - mu * C1s[hh]) + C0s[hh];
        bias_out[(size_t)hh * NPAIR + g] = mk ? bvv : -1e30f;
      }
    }
  }
}

// ---------------- K4: per (head, 8-row tile) attention + gate ----------------
// 256 threads = 8 rows x 32 lanes. Each wave owns 2 complete rows -> no barriers.
__global__ __launch_bounds__(256) void k_attn(const float* __restrict__ q,
                                              const float* __restrict__ k,
                                              const float* __restrict__ v,
                                              const float* __restrict__ gate,
                                              const float* __restrict__ bias,
                                              float* __restrict__ aout) {
  __shared__ __align__(16) float SIM[8 * 772];
  __shared__ __align__(16) float QS[256];
  int i0 = blockIdx.x * 8, h = blockIdx.y, t = threadIdx.x;
  int tr = t >> 5, tc = t & 31;
  QS[t] = q[((size_t)h * NT + i0 + tr) * DH + tc];   // t == tr*32+tc
  // QS row tr written & read by the same 32-lane group -> wave-coherent, no barrier
  float4 qr[8];
#pragma unroll
  for (int e = 0; e < 8; ++e) qr[e] = *(float4*)&QS[tr * 32 + e * 4];
  const float* Kh = k + (size_t)h * NT * DH;
  const float* Vh = v + (size_t)h * NT * DH;
  const float* brow = bias + ((size_t)h * NT + i0 + tr) * NT;
  float sv[24];
  float mx = -3.4e38f;
#pragma unroll
  for (int it = 0; it < 24; ++it) {
    int j = it * 32 + tc;
    const float4* kr = (const float4*)(Kh + j * DH);
    float s = 0.f;
#pragma unroll
    for (int e = 0; e < 8; ++e) {
      float4 kv = kr[e];
      s += qr[e].x * kv.x + qr[e].y * kv.y + qr[e].z * kv.z + qr[e].w * kv.w;
    }
    s += brow[j];                     // q pre-scaled; bias carries mask fold
    sv[it] = s;
    mx = fmaxf(mx, s);
  }
#pragma unroll
  for (int m = 1; m < 32; m <<= 1) mx = fmaxf(mx, __shfl_xor(mx, m));
  float sum = 0.f;
#pragma unroll
  for (int it = 0; it < 24; ++it) {
    float p = __expf(sv[it] - mx);
    SIM[tr * 772 + it * 32 + tc] = p;
    sum += p;
  }
#pragma unroll
  for (int m = 1; m < 32; m <<= 1) sum += __shfl_xor(sum, m);
  float inv = 1.f / sum;
  // PV: row tr's SIM written by this wave's own 32-lane group -> no barrier
  float acc = 0.f;
#pragma unroll 8
  for (int j = 0; j < NT; ++j) {
    acc = fmaf(SIM[tr * 772 + j], Vh[j * DH + tc], acc);
  }
  acc *= inv;
  int i = i0 + tr;
  float gg = gate[i * ND + h * DH + tc];
  aout[i * ND + h * DH + tc] = acc * gg;
}

// ---------------- K5: aout @ w_out + b_out -> fp32 output ----------------
__global__ __launch_bounds__(256) void k_proj(const float* __restrict__ a,
                                              const float* __restrict__ w,
                                              const float* __restrict__ b,
                                              float* __restrict__ out) {
  __shared__ __align__(16) float As[16 * 64];
  __shared__ __align__(16) float Bs[16 * 64];
  int n0 = blockIdx.x * 64, i0 = blockIdx.y * 64, t = threadIdx.x;
  int tm = t >> 4, tn = t & 15;
  int sm = t >> 2, sk = (t & 3) * 4;
  int bk = t >> 4, bn = (t & 15) * 4;
  float acc[4][4] = {{0.f}};
  for (int k0 = 0; k0 < 256; k0 += 16) {
    float4 av = *(const float4*)&a[(i0 + sm) * 256 + k0 + sk];
    float4 bv = *(const float4*)&w[(k0 + bk) * 256 + n0 + bn];
    __syncthreads();
    As[(sk + 0) * 64 + sm] = av.x; As[(sk + 1) * 64 + sm] = av.y;
    As[(sk + 2) * 64 + sm] = av.z; As[(sk + 3) * 64 + sm] = av.w;
    *(float4*)&Bs[bk * 64 + bn] = bv;
    __syncthreads();
#pragma unroll
    for (int kk = 0; kk < 16; ++kk) {
      float4 a4 = *(float4*)&As[kk * 64 + tm * 4];
      float4 b4 = *(float4*)&Bs[kk * 64 + tn * 4];
      float ar[4] = {a4.x, a4.y, a4.z, a4.w};
      float br[4] = {b4.x, b4.y, b4.z, b4.w};
#pragma unroll
      for (int ii = 0; ii < 4; ++ii)
#pragma unroll
        for (int jj = 0; jj < 4; ++jj) acc[ii][jj] = fmaf(ar[ii], br[jj], acc[ii][jj]);
    }
  }
#pragma unroll
  for (int ii = 0; ii < 4; ++ii) {
    int i = i0 + tm * 4 + ii;
#pragma unroll
    for (int jj = 0; jj < 4; ++jj) {
      int o = n0 + tn * 4 + jj;
      out[i * 256 + o] = acc[ii][jj] + b[o];
    }
  }
}

extern "C" void kernel_launch(void* const* d_in, const int* in_sizes, int n_in,
                              void* d_out, int out_size, void* d_ws, size_t ws_size,
                              hipStream_t stream) {
  const float* node   = (const float*)d_in[0];
  const float* pair   = (const float*)d_in[1];
  const int*   mask   = (const int*)d_in[2];
  const float* ln_nw  = (const float*)d_in[3];
  const float* ln_nb  = (const float*)d_in[4];
  const float* ln_pw  = (const float*)d_in[5];
  const float* ln_pb  = (const float*)d_in[6];
  const float* w_qkv  = (const float*)d_in[7];
  const float* w_g    = (const float*)d_in[8];
  const float* b_g    = (const float*)d_in[9];
  const float* w_bias = (const float*)d_in[10];
  const float* w_out  = (const float*)d_in[11];
  const float* b_out  = (const float*)d_in[12];
  float* ws = (float*)d_ws;
  float* out = (float*)d_out;

  k_pair_bias<<<NPAIR / 96, 256, 0, stream>>>(pair, mask, ln_pw, ln_pb, w_bias, ws + WS_BIAS);
  k_ln_node<<<NT, 256, 0, stream>>>(node, ln_nw, ln_nb, ws + WS_X);
  k_qkvg<<<dim3(16, 12), 256, 0, stream>>>(ws + WS_X, w_qkv, w_g, b_g, ws);
  k_attn<<<dim3(96, 8), 256, 0, stream>>>(ws + WS_Q, ws + WS_K, ws + WS_V,
                                          ws + WS_GATE, ws + WS_BIAS, ws + WS_AOUT);
  k_proj<<<dim3(4, 12), 256, 0, stream>>>(ws + WS_AOUT, w_out, b_out, out);
}

// Round 4
// 229.542 us; speedup vs baseline: 1.3390x; 1.1867x over previous
//
#include <hip/hip_runtime.h>
#include <hip/hip_bf16.h>

#define NT 768
#define ND 256
#define PD 128
#define NH 8
#define DH 32
#define NPAIR 589824   // 768*768

// workspace offsets (floats)
#define WS_X     0
#define WS_Q     196608
#define WS_K     393216
#define WS_V     589824
#define WS_GATE  786432
#define WS_AOUT  983040
#define WS_BIAS  1179648
#define WS_WPT   5898240   // 1024 floats: wpt[h][e] = ln_w[e]*wb[e][h]
#define WS_C01   5899264   // c0[0..7], c1[0..7]
// total = 5899280 floats = 23.6 MB

// ---------------- K0: precompute WPT, C0, C1 (one block) ----------------
__global__ __launch_bounds__(256) void k_prep(const float* __restrict__ lnw,
                                              const float* __restrict__ lnb,
                                              const float* __restrict__ wb,
                                              float* __restrict__ wpt,
                                              float* __restrict__ c01) {
  __shared__ float PS0[256], PS1[256];
  int t = threadIdx.x;
#pragma unroll
  for (int i = 0; i < 4; ++i) {
    int idx = t + 256 * i;
    int h = idx >> 7, e = idx & 127;
    wpt[h * 128 + e] = lnw[e] * wb[e * 8 + h];
  }
  int h = t & 7, seg = t >> 3;          // seg 0..31 covers e = 4*seg..+3
  float a0 = 0.f, a1 = 0.f;
#pragma unroll
  for (int k = 0; k < 4; ++k) {
    int e = seg * 4 + k;
    float wv = wb[e * 8 + h];
    a0 = fmaf(lnb[e], wv, a0);
    a1 = fmaf(lnw[e], wv, a1);
  }
  PS0[t] = a0; PS1[t] = a1;
  __syncthreads();
  if (t < 16) {
    int hh = t & 7; bool isc1 = t >= 8;
    float s = 0.f;
    for (int sg = 0; sg < 32; ++sg) s += (isc1 ? PS1 : PS0)[sg * 8 + hh];
    c01[t] = s;
  }
}

// ---------------- K1: LayerNorm(node) -> x ----------------
__global__ __launch_bounds__(256) void k_ln_node(const float* __restrict__ nf,
                                                 const float* __restrict__ w,
                                                 const float* __restrict__ b,
                                                 float* __restrict__ x) {
  int i = blockIdx.x, t = threadIdx.x;
  float v = nf[i * ND + t];
  float s1 = v, s2 = v * v;
#pragma unroll
  for (int m = 1; m < 64; m <<= 1) { s1 += __shfl_xor(s1, m); s2 += __shfl_xor(s2, m); }
  __shared__ float a1[4], a2[4];
  if ((t & 63) == 0) { a1[t >> 6] = s1; a2[t >> 6] = s2; }
  __syncthreads();
  s1 = a1[0] + a1[1] + a1[2] + a1[3];
  s2 = a2[0] + a2[1] + a2[2] + a2[3];
  float mu = s1 * (1.f / ND);
  float var = s2 * (1.f / ND) - mu * mu;
  float rs = rsqrtf(var + 1e-5f);
  x[i * ND + t] = (v - mu) * rs * w[t] + b[t];
}

// ---------------- K2: x @ [w_qkv | w_g] -> q,k,v (h,i,d) + sigmoid gate ----------------
__global__ __launch_bounds__(256) void k_qkvg(const float* __restrict__ x,
                                              const float* __restrict__ wqkv,
                                              const float* __restrict__ wg,
                                              const float* __restrict__ bg,
                                              float* __restrict__ ws) {
  __shared__ __align__(16) float As[16 * 64];
  __shared__ __align__(16) float Bs[16 * 64];
  int n0 = blockIdx.x * 64, i0 = blockIdx.y * 64, t = threadIdx.x;
  bool isg = (n0 >= 768);
  const float* W = isg ? wg : wqkv;
  int ldb = isg ? 256 : 768;
  int nc0 = isg ? n0 - 768 : n0;
  int tm = t >> 4, tn = t & 15;
  int sm = t >> 2, sk = (t & 3) * 4;
  int bk = t >> 4, bn = (t & 15) * 4;
  float acc[4][4] = {{0.f}};
  for (int k0 = 0; k0 < 256; k0 += 16) {
    float4 av = *(const float4*)&x[(i0 + sm) * 256 + k0 + sk];
    float4 bv = *(const float4*)&W[(size_t)(k0 + bk) * ldb + nc0 + bn];
    __syncthreads();
    As[(sk + 0) * 64 + sm] = av.x; As[(sk + 1) * 64 + sm] = av.y;
    As[(sk + 2) * 64 + sm] = av.z; As[(sk + 3) * 64 + sm] = av.w;
    *(float4*)&Bs[bk * 64 + bn] = bv;
    __syncthreads();
#pragma unroll
    for (int kk = 0; kk < 16; ++kk) {
      float4 a4 = *(float4*)&As[kk * 64 + tm * 4];
      float4 b4 = *(float4*)&Bs[kk * 64 + tn * 4];
      float ar[4] = {a4.x, a4.y, a4.z, a4.w};
      float br[4] = {b4.x, b4.y, b4.z, b4.w};
#pragma unroll
      for (int ii = 0; ii < 4; ++ii)
#pragma unroll
        for (int jj = 0; jj < 4; ++jj) acc[ii][jj] = fmaf(ar[ii], br[jj], acc[ii][jj]);
    }
  }
#pragma unroll
  for (int ii = 0; ii < 4; ++ii) {
    int i = i0 + tm * 4 + ii;
#pragma unroll
    for (int jj = 0; jj < 4; ++jj) {
      int o = n0 + tn * 4 + jj;
      float val = acc[ii][jj];
      if (!isg) {
        int which = o >> 8, inner = o & 255, h = inner >> 5, d = inner & 31;
        float* dst = ws + (which == 0 ? WS_Q : (which == 1 ? WS_K : WS_V));
        float sc = (which == 0) ? 0.17677669529663687f : 1.f;  // 1/sqrt(32) on q
        dst[(h * NT + i) * DH + d] = val * sc;
      } else {
        int inner = nc0 + tn * 4 + jj;
        val += bg[inner];
        ws[WS_GATE + i * ND + inner] = 1.f / (1.f + __expf(-val));
      }
    }
  }
}

// ---------------- K3: fused LN(pair) @ w_bias + mask fold -> bias (h,i,j) ----------------
// LDS-free streaming: each 4-lane quad owns 4 rows; lane q reads chunks e4=q+4*it.
// Quad butterfly reduces 8 head-dots; lane q ends with heads {4*(q&1)+2*(q>>1), +1}.
__global__ __launch_bounds__(256) void k_pair_bias(const float* __restrict__ pf,
                                                   const int* __restrict__ mask,
                                                   const float* __restrict__ wpt,
                                                   const float* __restrict__ c01,
                                                   float* __restrict__ bias_out) {
  int t = threadIdx.x;
  int q = t & 3;            // chunk lane within quad
  int j = (t >> 2) & 15;    // quad index within wave
  int w = t >> 6;           // wave in block
  size_t base = ((size_t)blockIdx.x * 4 + w) * 64;   // this wave's 64 rows
  float d[4][8] = {{0.f}};
  float s1[4] = {0.f, 0.f, 0.f, 0.f};
  float s2[4] = {0.f, 0.f, 0.f, 0.f};
#pragma unroll
  for (int it = 0; it < 8; ++it) {
    int e4 = q + 4 * it;
    float4 p[4];
#pragma unroll
    for (int g = 0; g < 4; ++g)
      p[g] = *(const float4*)(pf + (base + 16 * g + j) * 128 + e4 * 4);
#pragma unroll
    for (int g = 0; g < 4; ++g) {
      s1[g] += p[g].x + p[g].y + p[g].z + p[g].w;
      s2[g] = fmaf(p[g].x, p[g].x, fmaf(p[g].y, p[g].y,
               fmaf(p[g].z, p[g].z, fmaf(p[g].w, p[g].w, s2[g]))));
    }
#pragma unroll
    for (int h = 0; h < 8; ++h) {
      float4 wv = *(const float4*)(wpt + h * 128 + e4 * 4);   // L1-resident 4KB table
#pragma unroll
      for (int g = 0; g < 4; ++g)
        d[g][h] = fmaf(p[g].x, wv.x, fmaf(p[g].y, wv.y,
                   fmaf(p[g].z, wv.z, fmaf(p[g].w, wv.w, d[g][h]))));
    }
  }
  int h0 = 4 * (q & 1) + 2 * (q >> 1);   // this lane's 2 output heads
  float c0a = c01[h0], c0b = c01[h0 + 1];
  float c1a = c01[8 + h0], c1b = c01[8 + h0 + 1];
#pragma unroll
  for (int g = 0; g < 4; ++g) {
    // butterfly step 1 (xor 1): 8 partial heads -> 4
    float m[4];
#pragma unroll
    for (int i = 0; i < 4; ++i) {
      float send = (q & 1) ? d[g][i] : d[g][i + 4];
      float keep = (q & 1) ? d[g][i + 4] : d[g][i];
      m[i] = keep + __shfl_xor(send, 1);
    }
    // step 2 (xor 2): 4 -> 2
    float n0, n1;
    {
      float send0 = (q & 2) ? m[0] : m[2];
      float keep0 = (q & 2) ? m[2] : m[0];
      n0 = keep0 + __shfl_xor(send0, 2);
      float send1 = (q & 2) ? m[1] : m[3];
      float keep1 = (q & 2) ? m[3] : m[1];
      n1 = keep1 + __shfl_xor(send1, 2);
    }
    float a = s1[g], b = s2[g];
    a += __shfl_xor(a, 1); a += __shfl_xor(a, 2);
    b += __shfl_xor(b, 1); b += __shfl_xor(b, 2);
    size_t row = base + 16 * g + j;
    float mu = a * (1.f / 128.f);
    float var = b * (1.f / 128.f) - mu * mu;
    float rs = rsqrtf(var + 1e-5f);
    int mk = mask[row];
    float bv0 = rs * (n0 - mu * c1a) + c0a;
    float bv1 = rs * (n1 - mu * c1b) + c0b;
    bias_out[(size_t)h0 * NPAIR + row] = mk ? bv0 : -1e30f;
    bias_out[(size_t)(h0 + 1) * NPAIR + row] = mk ? bv1 : -1e30f;
  }
}

// ---------------- K4: per (head, 8-row tile) attention + gate ----------------
// 256 threads = 8 rows x 32 lanes. Each wave owns 2 complete rows -> no barriers.
__global__ __launch_bounds__(256) void k_attn(const float* __restrict__ q,
                                              const float* __restrict__ k,
                                              const float* __restrict__ v,
                                              const float* __restrict__ gate,
                                              const float* __restrict__ bias,
                                              float* __restrict__ aout) {
  __shared__ __align__(16) float SIM[8 * 772];
  __shared__ __align__(16) float QS[256];
  int i0 = blockIdx.x * 8, h = blockIdx.y, t = threadIdx.x;
  int tr = t >> 5, tc = t & 31;
  QS[t] = q[((size_t)h * NT + i0 + tr) * DH + tc];   // t == tr*32+tc
  float4 qr[8];
#pragma unroll
  for (int e = 0; e < 8; ++e) qr[e] = *(float4*)&QS[tr * 32 + e * 4];
  const float* Kh = k + (size_t)h * NT * DH;
  const float* Vh = v + (size_t)h * NT * DH;
  const float* brow = bias + ((size_t)h * NT + i0 + tr) * NT;
  float sv[24];
  float mx = -3.4e38f;
#pragma unroll
  for (int it = 0; it < 24; ++it) {
    int j = it * 32 + tc;
    const float4* kr = (const float4*)(Kh + j * DH);
    float s = 0.f;
#pragma unroll
    for (int e = 0; e < 8; ++e) {
      float4 kv = kr[e];
      s += qr[e].x * kv.x + qr[e].y * kv.y + qr[e].z * kv.z + qr[e].w * kv.w;
    }
    s += brow[j];                     // q pre-scaled; bias carries mask fold
    sv[it] = s;
    mx = fmaxf(mx, s);
  }
#pragma unroll
  for (int m = 1; m < 32; m <<= 1) mx = fmaxf(mx, __shfl_xor(mx, m));
  float sum = 0.f;
#pragma unroll
  for (int it = 0; it < 24; ++it) {
    float p = __expf(sv[it] - mx);
    SIM[tr * 772 + it * 32 + tc] = p;
    sum += p;
  }
#pragma unroll
  for (int m = 1; m < 32; m <<= 1) sum += __shfl_xor(sum, m);
  float inv = 1.f / sum;
  float acc = 0.f;
#pragma unroll 8
  for (int j = 0; j < NT; ++j) {
    acc = fmaf(SIM[tr * 772 + j], Vh[j * DH + tc], acc);
  }
  acc *= inv;
  int i = i0 + tr;
  float gg = gate[i * ND + h * DH + tc];
  aout[i * ND + h * DH + tc] = acc * gg;
}

// ---------------- K5: aout @ w_out + b_out -> fp32 output ----------------
__global__ __launch_bounds__(256) void k_proj(const float* __restrict__ a,
                                              const float* __restrict__ w,
                                              const float* __restrict__ b,
                                              float* __restrict__ out) {
  __shared__ __align__(16) float As[16 * 64];
  __shared__ __align__(16) float Bs[16 * 64];
  int n0 = blockIdx.x * 64, i0 = blockIdx.y * 64, t = threadIdx.x;
  int tm = t >> 4, tn = t & 15;
  int sm = t >> 2, sk = (t & 3) * 4;
  int bk = t >> 4, bn = (t & 15) * 4;
  float acc[4][4] = {{0.f}};
  for (int k0 = 0; k0 < 256; k0 += 16) {
    float4 av = *(const float4*)&a[(i0 + sm) * 256 + k0 + sk];
    float4 bv = *(const float4*)&w[(k0 + bk) * 256 + n0 + bn];
    __syncthreads();
    As[(sk + 0) * 64 + sm] = av.x; As[(sk + 1) * 64 + sm] = av.y;
    As[(sk + 2) * 64 + sm] = av.z; As[(sk + 3) * 64 + sm] = av.w;
    *(float4*)&Bs[bk * 64 + bn] = bv;
    __syncthreads();
#pragma unroll
    for (int kk = 0; kk < 16; ++kk) {
      float4 a4 = *(float4*)&As[kk * 64 + tm * 4];
      float4 b4 = *(float4*)&Bs[kk * 64 + tn * 4];
      float ar[4] = {a4.x, a4.y, a4.z, a4.w};
      float br[4] = {b4.x, b4.y, b4.z, b4.w};
#pragma unroll
      for (int ii = 0; ii < 4; ++ii)
#pragma unroll
        for (int jj = 0; jj < 4; ++jj) acc[ii][jj] = fmaf(ar[ii], br[jj], acc[ii][jj]);
    }
  }
#pragma unroll
  for (int ii = 0; ii < 4; ++ii) {
    int i = i0 + tm * 4 + ii;
#pragma unroll
    for (int jj = 0; jj < 4; ++jj) {
      int o = n0 + tn * 4 + jj;
      out[i * 256 + o] = acc[ii][jj] + b[o];
    }
  }
}

extern "C" void kernel_launch(void* const* d_in, const int* in_sizes, int n_in,
                              void* d_out, int out_size, void* d_ws, size_t ws_size,
                              hipStream_t stream) {
  const float* node   = (const float*)d_in[0];
  const float* pair   = (const float*)d_in[1];
  const int*   mask   = (const int*)d_in[2];
  const float* ln_nw  = (const float*)d_in[3];
  const float* ln_nb  = (const float*)d_in[4];
  const float* ln_pw  = (const float*)d_in[5];
  const float* ln_pb  = (const float*)d_in[6];
  const float* w_qkv  = (const float*)d_in[7];
  const float* w_g    = (const float*)d_in[8];
  const float* b_g    = (const float*)d_in[9];
  const float* w_bias = (const float*)d_in[10];
  const float* w_out  = (const float*)d_in[11];
  const float* b_out  = (const float*)d_in[12];
  float* ws = (float*)d_ws;
  float* out = (float*)d_out;

  k_prep<<<1, 256, 0, stream>>>(ln_pw, ln_pb, w_bias, ws + WS_WPT, ws + WS_C01);
  k_pair_bias<<<NPAIR / 256, 256, 0, stream>>>(pair, mask, ws + WS_WPT, ws + WS_C01,
                                               ws + WS_BIAS);
  k_ln_node<<<NT, 256, 0, stream>>>(node, ln_nw, ln_nb, ws + WS_X);
  k_qkvg<<<dim3(16, 12), 256, 0, stream>>>(ws + WS_X, w_qkv, w_g, b_g, ws);
  k_attn<<<dim3(96, 8), 256, 0, stream>>>(ws + WS_Q, ws + WS_K, ws + WS_V,
                                          ws + WS_GATE, ws + WS_BIAS, ws + WS_AOUT);
  k_proj<<<dim3(4, 12), 256, 0, stream>>>(ws + WS_AOUT, w_out, b_out, out);
}

// Round 5
// 203.309 us; speedup vs baseline: 1.5118x; 1.1290x over previous
//
#include <hip/hip_runtime.h>
#include <hip/hip_bf16.h>

#define NT 768
#define ND 256
#define PD 128
#define NH 8
#define DH 32
#define NPAIR 589824   // 768*768

// workspace offsets (floats)
#define WS_X     0
#define WS_Q     196608
#define WS_K     393216
#define WS_V     589824
#define WS_GATE  786432
#define WS_AOUT  983040
#define WS_BIAS  1179648
#define WS_WPT   5898240   // 1024 floats: wpt[h][e] = ln_w[e]*wb[e][h]
#define WS_C01   5899264   // c0[0..7], c1[0..7]
// total = 5899280 floats = 23.6 MB

typedef float f32x2 __attribute__((ext_vector_type(2)));
static __device__ __forceinline__ f32x2 pkfma(f32x2 a, f32x2 b, f32x2 c) {
  return __builtin_elementwise_fma(a, b, c);
}

// ---------------- K0: precompute WPT, C0, C1 (one block) ----------------
__global__ __launch_bounds__(256) void k_prep(const float* __restrict__ lnw,
                                              const float* __restrict__ lnb,
                                              const float* __restrict__ wb,
                                              float* __restrict__ wpt,
                                              float* __restrict__ c01) {
  __shared__ float PS0[256], PS1[256];
  int t = threadIdx.x;
#pragma unroll
  for (int i = 0; i < 4; ++i) {
    int idx = t + 256 * i;
    int h = idx >> 7, e = idx & 127;
    wpt[h * 128 + e] = lnw[e] * wb[e * 8 + h];
  }
  int h = t & 7, seg = t >> 3;          // seg 0..31 covers e = 4*seg..+3
  float a0 = 0.f, a1 = 0.f;
#pragma unroll
  for (int k = 0; k < 4; ++k) {
    int e = seg * 4 + k;
    float wv = wb[e * 8 + h];
    a0 = fmaf(lnb[e], wv, a0);
    a1 = fmaf(lnw[e], wv, a1);
  }
  PS0[t] = a0; PS1[t] = a1;
  __syncthreads();
  if (t < 16) {
    int hh = t & 7; bool isc1 = t >= 8;
    float s = 0.f;
    for (int sg = 0; sg < 32; ++sg) s += (isc1 ? PS1 : PS0)[sg * 8 + hh];
    c01[t] = s;
  }
}

// ---------------- K1: LayerNorm(node) -> x ----------------
__global__ __launch_bounds__(256) void k_ln_node(const float* __restrict__ nf,
                                                 const float* __restrict__ w,
                                                 const float* __restrict__ b,
                                                 float* __restrict__ x) {
  int i = blockIdx.x, t = threadIdx.x;
  float v = nf[i * ND + t];
  float s1 = v, s2 = v * v;
#pragma unroll
  for (int m = 1; m < 64; m <<= 1) { s1 += __shfl_xor(s1, m); s2 += __shfl_xor(s2, m); }
  __shared__ float a1[4], a2[4];
  if ((t & 63) == 0) { a1[t >> 6] = s1; a2[t >> 6] = s2; }
  __syncthreads();
  s1 = a1[0] + a1[1] + a1[2] + a1[3];
  s2 = a2[0] + a2[1] + a2[2] + a2[3];
  float mu = s1 * (1.f / ND);
  float var = s2 * (1.f / ND) - mu * mu;
  float rs = rsqrtf(var + 1e-5f);
  x[i * ND + t] = (v - mu) * rs * w[t] + b[t];
}

// ---------------- K2: x @ [w_qkv | w_g] -> q,k,v (h,i,d) + sigmoid gate ----------------
__global__ __launch_bounds__(256) void k_qkvg(const float* __restrict__ x,
                                              const float* __restrict__ wqkv,
                                              const float* __restrict__ wg,
                                              const float* __restrict__ bg,
                                              float* __restrict__ ws) {
  __shared__ __align__(16) float As[16 * 64];
  __shared__ __align__(16) float Bs[16 * 64];
  int n0 = blockIdx.x * 64, i0 = blockIdx.y * 64, t = threadIdx.x;
  bool isg = (n0 >= 768);
  const float* W = isg ? wg : wqkv;
  int ldb = isg ? 256 : 768;
  int nc0 = isg ? n0 - 768 : n0;
  int tm = t >> 4, tn = t & 15;
  int sm = t >> 2, sk = (t & 3) * 4;
  int bk = t >> 4, bn = (t & 15) * 4;
  float acc[4][4] = {{0.f}};
  for (int k0 = 0; k0 < 256; k0 += 16) {
    float4 av = *(const float4*)&x[(i0 + sm) * 256 + k0 + sk];
    float4 bv = *(const float4*)&W[(size_t)(k0 + bk) * ldb + nc0 + bn];
    __syncthreads();
    As[(sk + 0) * 64 + sm] = av.x; As[(sk + 1) * 64 + sm] = av.y;
    As[(sk + 2) * 64 + sm] = av.z; As[(sk + 3) * 64 + sm] = av.w;
    *(float4*)&Bs[bk * 64 + bn] = bv;
    __syncthreads();
#pragma unroll
    for (int kk = 0; kk < 16; ++kk) {
      float4 a4 = *(float4*)&As[kk * 64 + tm * 4];
      float4 b4 = *(float4*)&Bs[kk * 64 + tn * 4];
      float ar[4] = {a4.x, a4.y, a4.z, a4.w};
      float br[4] = {b4.x, b4.y, b4.z, b4.w};
#pragma unroll
      for (int ii = 0; ii < 4; ++ii)
#pragma unroll
        for (int jj = 0; jj < 4; ++jj) acc[ii][jj] = fmaf(ar[ii], br[jj], acc[ii][jj]);
    }
  }
#pragma unroll
  for (int ii = 0; ii < 4; ++ii) {
    int i = i0 + tm * 4 + ii;
#pragma unroll
    for (int jj = 0; jj < 4; ++jj) {
      int o = n0 + tn * 4 + jj;
      float val = acc[ii][jj];
      if (!isg) {
        int which = o >> 8, inner = o & 255, h = inner >> 5, d = inner & 31;
        float* dst = ws + (which == 0 ? WS_Q : (which == 1 ? WS_K : WS_V));
        float sc = (which == 0) ? 0.17677669529663687f : 1.f;  // 1/sqrt(32) on q
        dst[(h * NT + i) * DH + d] = val * sc;
      } else {
        int inner = nc0 + tn * 4 + jj;
        val += bg[inner];
        ws[WS_GATE + i * ND + inner] = 1.f / (1.f + __expf(-val));
      }
    }
  }
}

// ---------------- K3: fused LN(pair) @ w_bias + mask fold -> bias (h,i,j) ----------------
// v3: 16 lanes per row x 4 rows per wave-instr. wpt preloaded in regs (f32x2),
// packed-fma dots, 4-step value-exchange butterfly, wave-private LDS output
// staging, mask folded at the final coalesced store. No barriers.
__global__ __launch_bounds__(256, 4) void k_pair_bias(const float* __restrict__ pf,
                                                      const int* __restrict__ mask,
                                                      const float* __restrict__ wpt,
                                                      const float* __restrict__ c01,
                                                      float* __restrict__ bias_out) {
  __shared__ float OB[4][8 * 65];       // per-wave: 8 heads x 64 rows (pad 65)
  int t = threadIdx.x;
  int w = t >> 6, lane = t & 63;
  int c = lane & 15;                    // channel-lane: float4 chunks {c, c+16}
  int g = lane >> 4;                    // row group 0..3
  size_t wbase = ((size_t)blockIdx.x * 4 + w) * 64;   // this wave's 64 rows
  int hme = (lane >> 1) & 7;            // head this lane owns after reduction
  // preload wpt slices for this lane's 8 channels, all 8 heads (64 VGPR)
  f32x2 b0[8], b1[8], b2[8], b3[8];
#pragma unroll
  for (int h = 0; h < 8; ++h) {
    float4 w0 = *(const float4*)(wpt + h * 128 + c * 4);
    float4 w1 = *(const float4*)(wpt + h * 128 + (c + 16) * 4);
    b0[h] = (f32x2){w0.x, w0.y}; b1[h] = (f32x2){w0.z, w0.w};
    b2[h] = (f32x2){w1.x, w1.y}; b3[h] = (f32x2){w1.z, w1.w};
  }
  float c0me = c01[hme], c1me = c01[8 + hme];
  bool bit3 = (lane & 8) != 0, bit2 = (lane & 4) != 0, bit1 = (lane & 2) != 0;
#pragma unroll
  for (int it = 0; it < 16; ++it) {
    int r = it * 4 + g;                 // row within wave's 64
    const float* prow = pf + (wbase + r) * 128;
    float4 p0 = *(const float4*)(prow + c * 4);
    float4 p1 = *(const float4*)(prow + (c + 16) * 4);
    f32x2 a0 = (f32x2){p0.x, p0.y}, a1 = (f32x2){p0.z, p0.w};
    f32x2 a2 = (f32x2){p1.x, p1.y}, a3 = (f32x2){p1.z, p1.w};
    // s1/s2 over this lane's 8 channels (packed)
    f32x2 sv1 = a0 + a1 + a2 + a3;
    f32x2 sv2 = pkfma(a0, a0, pkfma(a1, a1, pkfma(a2, a2, pkfma(a3, a3, (f32x2){0.f, 0.f}))));
    float s1 = sv1.x + sv1.y;
    float s2 = sv2.x + sv2.y;
    // 8 head-dot partials (packed fma)
    float d[8];
#pragma unroll
    for (int h = 0; h < 8; ++h) {
      f32x2 acc = pkfma(a0, b0[h], pkfma(a1, b1[h], pkfma(a2, b2[h], pkfma(a3, b3[h], (f32x2){0.f, 0.f}))));
      d[h] = acc.x + acc.y;
    }
    // butterfly: reduce over 16 lanes while splitting 8 heads across lanes
    float m0, m1, m2, m3;
    m0 = (bit3 ? d[4] : d[0]) + __shfl_xor(bit3 ? d[0] : d[4], 8);
    m1 = (bit3 ? d[5] : d[1]) + __shfl_xor(bit3 ? d[1] : d[5], 8);
    m2 = (bit3 ? d[6] : d[2]) + __shfl_xor(bit3 ? d[2] : d[6], 8);
    m3 = (bit3 ? d[7] : d[3]) + __shfl_xor(bit3 ? d[3] : d[7], 8);
    float n0, n1;
    n0 = (bit2 ? m2 : m0) + __shfl_xor(bit2 ? m0 : m2, 4);
    n1 = (bit2 ? m3 : m1) + __shfl_xor(bit2 ? m1 : m3, 4);
    float o = (bit1 ? n1 : n0) + __shfl_xor(bit1 ? n0 : n1, 2);
    o += __shfl_xor(o, 1);
    // s1,s2 full reduce over 16 lanes
    s1 += __shfl_xor(s1, 1); s1 += __shfl_xor(s1, 2);
    s1 += __shfl_xor(s1, 4); s1 += __shfl_xor(s1, 8);
    s2 += __shfl_xor(s2, 1); s2 += __shfl_xor(s2, 2);
    s2 += __shfl_xor(s2, 4); s2 += __shfl_xor(s2, 8);
    float mu = s1 * (1.f / 128.f);
    float var = s2 * (1.f / 128.f) - mu * mu;
    float rs = rsqrtf(var + 1e-5f);
    float bv = rs * (o - mu * c1me) + c0me;
    if ((lane & 1) == 0) OB[w][hme * 65 + r] = bv;
  }
  // final phase: mask fold + coalesced per-head stores (wave-private, no barrier)
  int mk = mask[wbase + lane];
#pragma unroll
  for (int h = 0; h < 8; ++h) {
    float v = OB[w][h * 65 + lane];
    bias_out[(size_t)h * NPAIR + wbase + lane] = mk ? v : -1e30f;
  }
}

// ---------------- K4: per (head, 8-row tile) attention + gate ----------------
// 256 threads = 8 rows x 32 lanes. Each wave owns 2 complete rows -> no barriers.
__global__ __launch_bounds__(256) void k_attn(const float* __restrict__ q,
                                              const float* __restrict__ k,
                                              const float* __restrict__ v,
                                              const float* __restrict__ gate,
                                              const float* __restrict__ bias,
                                              float* __restrict__ aout) {
  __shared__ __align__(16) float SIM[8 * 772];
  __shared__ __align__(16) float QS[256];
  int i0 = blockIdx.x * 8, h = blockIdx.y, t = threadIdx.x;
  int tr = t >> 5, tc = t & 31;
  QS[t] = q[((size_t)h * NT + i0 + tr) * DH + tc];   // t == tr*32+tc
  float4 qr[8];
#pragma unroll
  for (int e = 0; e < 8; ++e) qr[e] = *(float4*)&QS[tr * 32 + e * 4];
  const float* Kh = k + (size_t)h * NT * DH;
  const float* Vh = v + (size_t)h * NT * DH;
  const float* brow = bias + ((size_t)h * NT + i0 + tr) * NT;
  float sv[24];
  float mx = -3.4e38f;
#pragma unroll
  for (int it = 0; it < 24; ++it) {
    int j = it * 32 + tc;
    const float4* kr = (const float4*)(Kh + j * DH);
    float s = 0.f;
#pragma unroll
    for (int e = 0; e < 8; ++e) {
      float4 kv = kr[e];
      s += qr[e].x * kv.x + qr[e].y * kv.y + qr[e].z * kv.z + qr[e].w * kv.w;
    }
    s += brow[j];                     // q pre-scaled; bias carries mask fold
    sv[it] = s;
    mx = fmaxf(mx, s);
  }
#pragma unroll
  for (int m = 1; m < 32; m <<= 1) mx = fmaxf(mx, __shfl_xor(mx, m));
  float sum = 0.f;
#pragma unroll
  for (int it = 0; it < 24; ++it) {
    float p = __expf(sv[it] - mx);
    SIM[tr * 772 + it * 32 + tc] = p;
    sum += p;
  }
#pragma unroll
  for (int m = 1; m < 32; m <<= 1) sum += __shfl_xor(sum, m);
  float inv = 1.f / sum;
  float acc = 0.f;
#pragma unroll 8
  for (int j = 0; j < NT; ++j) {
    acc = fmaf(SIM[tr * 772 + j], Vh[j * DH + tc], acc);
  }
  acc *= inv;
  int i = i0 + tr;
  float gg = gate[i * ND + h * DH + tc];
  aout[i * ND + h * DH + tc] = acc * gg;
}

// ---------------- K5: aout @ w_out + b_out -> fp32 output ----------------
__global__ __launch_bounds__(256) void k_proj(const float* __restrict__ a,
                                              const float* __restrict__ w,
                                              const float* __restrict__ b,
                                              float* __restrict__ out) {
  __shared__ __align__(16) float As[16 * 64];
  __shared__ __align__(16) float Bs[16 * 64];
  int n0 = blockIdx.x * 64, i0 = blockIdx.y * 64, t = threadIdx.x;
  int tm = t >> 4, tn = t & 15;
  int sm = t >> 2, sk = (t & 3) * 4;
  int bk = t >> 4, bn = (t & 15) * 4;
  float acc[4][4] = {{0.f}};
  for (int k0 = 0; k0 < 256; k0 += 16) {
    float4 av = *(const float4*)&a[(i0 + sm) * 256 + k0 + sk];
    float4 bv = *(const float4*)&w[(k0 + bk) * 256 + n0 + bn];
    __syncthreads();
    As[(sk + 0) * 64 + sm] = av.x; As[(sk + 1) * 64 + sm] = av.y;
    As[(sk + 2) * 64 + sm] = av.z; As[(sk + 3) * 64 + sm] = av.w;
    *(float4*)&Bs[bk * 64 + bn] = bv;
    __syncthreads();
#pragma unroll
    for (int kk = 0; kk < 16; ++kk) {
      float4 a4 = *(float4*)&As[kk * 64 + tm * 4];
      float4 b4 = *(float4*)&Bs[kk * 64 + tn * 4];
      float ar[4] = {a4.x, a4.y, a4.z, a4.w};
      float br[4] = {b4.x, b4.y, b4.z, b4.w};
#pragma unroll
      for (int ii = 0; ii < 4; ++ii)
#pragma unroll
        for (int jj = 0; jj < 4; ++jj) acc[ii][jj] = fmaf(ar[ii], br[jj], acc[ii][jj]);
    }
  }
#pragma unroll
  for (int ii = 0; ii < 4; ++ii) {
    int i = i0 + tm * 4 + ii;
#pragma unroll
    for (int jj = 0; jj < 4; ++jj) {
      int o = n0 + tn * 4 + jj;
      out[i * 256 + o] = acc[ii][jj] + b[o];
    }
  }
}

extern "C" void kernel_launch(void* const* d_in, const int* in_sizes, int n_in,
                              void* d_out, int out_size, void* d_ws, size_t ws_size,
                              hipStream_t stream) {
  const float* node   = (const float*)d_in[0];
  const float* pair   = (const float*)d_in[1];
  const int*   mask   = (const int*)d_in[2];
  const float* ln_nw  = (const float*)d_in[3];
  const float* ln_nb  = (const float*)d_in[4];
  const float* ln_pw  = (const float*)d_in[5];
  const float* ln_pb  = (const float*)d_in[6];
  const float* w_qkv  = (const float*)d_in[7];
  const float* w_g    = (const float*)d_in[8];
  const float* b_g    = (const float*)d_in[9];
  const float* w_bias = (const float*)d_in[10];
  const float* w_out  = (const float*)d_in[11];
  const float* b_out  = (const float*)d_in[12];
  float* ws = (float*)d_ws;
  float* out = (float*)d_out;

  k_prep<<<1, 256, 0, stream>>>(ln_pw, ln_pb, w_bias, ws + WS_WPT, ws + WS_C01);
  k_pair_bias<<<NPAIR / 256, 256, 0, stream>>>(pair, mask, ws + WS_WPT, ws + WS_C01,
                                               ws + WS_BIAS);
  k_ln_node<<<NT, 256, 0, stream>>>(node, ln_nw, ln_nb, ws + WS_X);
  k_qkvg<<<dim3(16, 12), 256, 0, stream>>>(ws + WS_X, w_qkv, w_g, b_g, ws);
  k_attn<<<dim3(96, 8), 256, 0, stream>>>(ws + WS_Q, ws + WS_K, ws + WS_V,
                                          ws + WS_GATE, ws + WS_BIAS, ws + WS_AOUT);
  k_proj<<<dim3(4, 12), 256, 0, stream>>>(ws + WS_AOUT, w_out, b_out, out);
}